// Round 5
// baseline (338.471 us; speedup 1.0000x reference)
//
#include <hip/hip_runtime.h>

// MHA forward: B=4, T=2048, D=1024, H=16, HD=64. bf16 MFMA pipeline.
typedef unsigned short u16;
typedef __attribute__((ext_vector_type(8))) __bf16 bf16x8;
typedef __attribute__((ext_vector_type(4))) float f32x4;
typedef __attribute__((ext_vector_type(16))) float f32x16;
typedef __attribute__((ext_vector_type(4))) unsigned u32x4;

#define B_  4
#define T_  2048
#define D_  1024
#define H_  16
#define HD_ 64
#define M_  (B_*T_)   // 8192 tokens

// RNE float -> bf16
__device__ __forceinline__ u16 f2bf(float x) {
  unsigned u = __float_as_uint(x);
  return (u16)((u + 0x7FFFu + ((u >> 16) & 1u)) >> 16);
}

__device__ __forceinline__ unsigned cvtpk(float lo, float hi) {
  unsigned r;
  asm("v_cvt_pk_bf16_f32 %0, %1, %2" : "=v"(r) : "v"(lo), "v"(hi));
  return r;
}

__device__ __forceinline__ float expraw(float x) {   // exp2, raw v_exp_f32
  float r;
  asm("v_exp_f32 %0, %1" : "=v"(r) : "v"(x));
  return r;
}

// async global->LDS, 16 bytes per lane (wave-uniform base + lane*16 dest)
__device__ __forceinline__ void async16(const void* g, void* lds) {
  __builtin_amdgcn_global_load_lds((__attribute__((address_space(1))) void*)g,
                                   (__attribute__((address_space(3))) void*)lds,
                                   16, 0, 0);
}

// ---------------- convert inputs fp32 -> bf16 ----------------
__global__ void k_convert_x(const float* __restrict__ x, u16* __restrict__ xb) {
  const int n4 = M_ * D_ / 4;
  for (int i = blockIdx.x * blockDim.x + threadIdx.x; i < n4; i += gridDim.x * blockDim.x) {
    float4 v = ((const float4*)x)[i];
    u16 o0 = f2bf(v.x), o1 = f2bf(v.y), o2 = f2bf(v.z), o3 = f2bf(v.w);
    unsigned lo = (unsigned)o0 | ((unsigned)o1 << 16);
    unsigned hi = (unsigned)o2 | ((unsigned)o3 << 16);
    ((uint2*)xb)[i] = make_uint2(lo, hi);
  }
}

// ---------------- transpose + convert weights ----------------
// z<3: write into WqkvT concat [3072][1024] (rows z*1024 + n). z==3: WoT.
__global__ void k_transpose_w(const float* __restrict__ Wq, const float* __restrict__ Wk,
                              const float* __restrict__ Wv, const float* __restrict__ Wo,
                              u16* __restrict__ WqkvT, u16* __restrict__ WoT) {
  __shared__ float tile[32][33];
  const float* W; u16* Wt;
  switch (blockIdx.z) {
    case 0:  W = Wq; Wt = WqkvT;               break;
    case 1:  W = Wk; Wt = WqkvT + 1024 * D_;   break;
    case 2:  W = Wv; Wt = WqkvT + 2048 * D_;   break;
    default: W = Wo; Wt = WoT;                 break;
  }
  int tx = threadIdx.x & 31, ty = threadIdx.x >> 5;  // 32 x 8
  int k0 = blockIdx.y * 32, n0 = blockIdx.x * 32;
#pragma unroll
  for (int i = 0; i < 4; i++) {
    int r = ty + i * 8;
    tile[r][tx] = W[(k0 + r) * D_ + n0 + tx];
  }
  __syncthreads();
#pragma unroll
  for (int i = 0; i < 4; i++) {
    int r = ty + i * 8;
    Wt[(n0 + r) * D_ + k0 + tx] = f2bf(tile[tx][r]);
  }
}

// ---------------- GEMM core: C[128x128] tile, A[M,1024] bf16 row-major, Bt[N,1024] bf16 row-major ----------------
__device__ __forceinline__ void gemm_tile(const u16* __restrict__ A, const u16* __restrict__ Bt,
                                          u16* Alds, u16* Blds,
                                          int m0, int n0, f32x4 acc[4][4]) {
  const int tid = threadIdx.x;
  const int l = tid & 63, w = tid >> 6;
  const int wm = (w >> 1) * 64, wn = (w & 1) * 64;
  const int lr = l & 15, lg = l >> 4;
  const f32x4 fz = {0.f, 0.f, 0.f, 0.f};
#pragma unroll
  for (int i = 0; i < 4; i++)
#pragma unroll
    for (int j = 0; j < 4; j++) acc[i][j] = fz;

  for (int kt = 0; kt < 1024; kt += 64) {
    __syncthreads();  // previous compute done before overwrite
#pragma unroll
    for (int i = 0; i < 4; i++) {
      int ch = tid + 256 * i;          // 0..1023 chunks of 8 bf16
      int r = ch >> 3, c8 = ch & 7;
      async16(A  + (m0 + r) * 1024 + kt + c8 * 8, Alds + ch * 8);
      async16(Bt + (n0 + r) * 1024 + kt + c8 * 8, Blds + ch * 8);
    }
    __syncthreads();  // staging drained
#pragma unroll
    for (int kk = 0; kk < 64; kk += 32) {
      bf16x8 af[4], bfr[4];
#pragma unroll
      for (int mi = 0; mi < 4; mi++)
        af[mi] = *(const bf16x8*)(Alds + (wm + mi * 16 + lr) * 64 + kk + lg * 8);
#pragma unroll
      for (int ni = 0; ni < 4; ni++)
        bfr[ni] = *(const bf16x8*)(Blds + (wn + ni * 16 + lr) * 64 + kk + lg * 8);
#pragma unroll
      for (int mi = 0; mi < 4; mi++)
#pragma unroll
        for (int ni = 0; ni < 4; ni++)
          acc[mi][ni] = __builtin_amdgcn_mfma_f32_16x16x32_bf16(af[mi], bfr[ni], acc[mi][ni], 0, 0, 0);
    }
  }
}

// Fused QKV GEMM over WqkvT [3072][1024]; output region by n range. bf16 out.
__global__ __launch_bounds__(256) void k_gemm_qkv(const u16* __restrict__ X,
                                                  const u16* __restrict__ WqkvT,
                                                  u16* __restrict__ Q, u16* __restrict__ K, u16* __restrict__ V) {
  __shared__ u16 Alds[128 * 64];
  __shared__ u16 Blds[128 * 64];
  int m0 = blockIdx.y * 128, n0 = blockIdx.x * 128;   // n0 in [0,3072)
  int reg = n0 >> 10;
  u16* Out = (reg == 0) ? Q : (reg == 1) ? K : V;
  int nb = n0 & 1023;
  f32x4 acc[4][4];
  gemm_tile(X, WqkvT, Alds, Blds, m0, n0, acc);
  const int l = threadIdx.x & 63, w = threadIdx.x >> 6;
  const int wm = (w >> 1) * 64, wn = (w & 1) * 64;
  const int lr = l & 15, lg = l >> 4;
#pragma unroll
  for (int mi = 0; mi < 4; mi++)
#pragma unroll
    for (int ni = 0; ni < 4; ni++)
#pragma unroll
      for (int r = 0; r < 4; r++) {
        int row = m0 + wm + mi * 16 + lg * 4 + r;
        int col = nb + wn + ni * 16 + lr;
        Out[row * D_ + col] = f2bf(acc[mi][ni][r]);
      }
}

// output GEMM: fp32 out + bias
__global__ __launch_bounds__(256) void k_gemm_out(const u16* __restrict__ Cx, const u16* __restrict__ WoT,
                                                  const float* __restrict__ bo, float* __restrict__ out) {
  __shared__ u16 Alds[128 * 64];
  __shared__ u16 Blds[128 * 64];
  int m0 = blockIdx.y * 128, n0 = blockIdx.x * 128;
  f32x4 acc[4][4];
  gemm_tile(Cx, WoT, Alds, Blds, m0, n0, acc);
  const int l = threadIdx.x & 63, w = threadIdx.x >> 6;
  const int wm = (w >> 1) * 64, wn = (w & 1) * 64;
  const int lr = l & 15, lg = l >> 4;
#pragma unroll
  for (int mi = 0; mi < 4; mi++)
#pragma unroll
    for (int ni = 0; ni < 4; ni++)
#pragma unroll
      for (int r = 0; r < 4; r++) {
        int row = m0 + wm + mi * 16 + lg * 4 + r;
        int col = n0 + wn + ni * 16 + lr;
        out[row * D_ + col] = acc[mi][ni][r] + bo[col];
      }
}

// ---------------- V transpose per (b,h): Vt[bh][d][t] ----------------
__global__ void k_transpose_v(const u16* __restrict__ V, u16* __restrict__ Vt) {
  __shared__ u16 tile[64][65];
  int bh = blockIdx.y;                 // b*H + h
  int b = bh >> 4, h = bh & 15;
  int t0 = blockIdx.x * 64;
  int tx = threadIdx.x & 63, ty = threadIdx.x >> 6;  // 64 x 4
#pragma unroll
  for (int i = 0; i < 16; i++) {
    int r = ty + i * 4;
    tile[r][tx] = V[(b * T_ + t0 + r) * D_ + h * HD_ + tx];
  }
  __syncthreads();
#pragma unroll
  for (int i = 0; i < 16; i++) {
    int d = ty + i * 4;
    Vt[((size_t)(bh * HD_ + d)) * T_ + t0 + tx] = tile[tx][d];
  }
}

// ---------------- flash attention (causal), no-LDS-staging version ----------------
// Block = 128 thr (2 waves). Wave = 32 q rows (QBLK=32). Block handles q-block pair
// {p, 63-p}: exactly 65 32-kv sub-tiles, split across the 2 waves by parity (33/32).
// Swapped QK^T (S^T = K*Q^T, 32x32x16): lane owns one q-row. K and V^T fragments read
// DIRECTLY from global (KV per (b,h) = 512KB, L2-resident; XCD swizzle pins 8 bh = 4MB
// per XCD L2). P^T in-register via cvt_pk + permlane32_swap. Fixed-shift softmax
// (exp2(s*EA+EB), shift-invariant => exact). No staging barriers; one LDS exchange per
// phase combines the two waves' partial (o, psum).
__global__ __launch_bounds__(128, 4) void k_flash(const u16* __restrict__ Q, const u16* __restrict__ Kb,
                                                  const u16* __restrict__ Vt, u16* __restrict__ ctx) {
  __shared__ float xo[2][2][64][17];   // [phase][wave][lane][16+pad]: given o-half
  __shared__ float xps[2][2][64];      // [phase][wave][lane]: partial psum
  // XCD swizzle: 2048 blocks; XCD c gets bh in [c*8, c*8+8)
  const int lin = blockIdx.x;
  const int c = lin & 7, idx = lin >> 3;      // idx 0..255
  const int bh = c * 8 + (idx >> 5);
  const int p = idx & 31;                      // pair index 0..31
  const int b = bh >> 4, h = bh & 15;
  const int tid = threadIdx.x, l = tid & 63, w = tid >> 6;
  const int q5 = l & 31, hi = l >> 5;
  // exp2(s*0.125*log2e - 12*log2e)
  const float EA = 0.18033688f, EB = -17.312340f;

  // per-lane global fragment bases (row = lane's kv/d row)
  const u16* Kbase  = Kb + (size_t)(b * T_ + q5) * D_ + h * HD_ + hi * 8;
  const u16* Vbase0 = Vt + (size_t)(bh * HD_ + q5) * T_ + hi * 8;        // d = q5
  const u16* Vbase1 = Vbase0 + (size_t)32 * T_;                          // d = 32 + q5

  for (int ph = 0; ph < 2; ph++) {
    const int qb = ph ? (63 - p) : p;
    const int qs = qb * 32;
    const int qa = qs + q5;            // this lane's q row

    // Q fragments: this lane's q-row, k-chunks of 8 at kc*16 + hi*8
    const u16* Qrow = Q + (size_t)(b * T_ + qa) * D_ + h * HD_;
    bf16x8 aQ[4];
#pragma unroll
    for (int kc = 0; kc < 4; kc++)
      aQ[kc] = *(const bf16x8*)(Qrow + kc * 16 + hi * 8);

    f32x16 o0 = {}, o1 = {};           // O^T partial: d 0..31 / 32..63, col q = q5
    float ps0 = 0.f, ps1 = 0.f, ps2 = 0.f, ps3 = 0.f;

    auto subtile = [&](int s, bool mask) __attribute__((always_inline)) {
      // S^T[kv32][q32] = K * Q^T
      f32x16 st = {};
      const u16* kp = Kbase + (size_t)s * 32 * D_;
#pragma unroll
      for (int kc = 0; kc < 4; kc++) {
        bf16x8 kf = *(const bf16x8*)(kp + kc * 16);
        st = __builtin_amdgcn_mfma_f32_32x32x16_bf16(kf, aQ[kc], st, 0, 0, 0);
      }
      // softmax: e = exp2(st*EA + EB); causal mask on last sub-tile only
      float e[16];
#pragma unroll
      for (int r = 0; r < 16; r++) {
        float ev = expraw(fmaf(st[r], EA, EB));
        if (mask) {
          int kva = s * 32 + (r & 3) + 8 * (r >> 2) + 4 * hi;
          if (kva > qa) ev = 0.f;
        }
        e[r] = ev;
      }
#pragma unroll
      for (int r = 0; r < 16; r += 4) {
        ps0 += e[r]; ps1 += e[r + 1]; ps2 += e[r + 2]; ps3 += e[r + 3];
      }
      // P^T B-frags in-register; PV: O^T += V^T * P^T
#pragma unroll
      for (int eh = 0; eh < 2; eh++) {
        unsigned a0 = cvtpk(e[eh * 8 + 0], e[eh * 8 + 1]);
        unsigned a1 = cvtpk(e[eh * 8 + 2], e[eh * 8 + 3]);
        unsigned b0 = cvtpk(e[eh * 8 + 4], e[eh * 8 + 5]);
        unsigned b1 = cvtpk(e[eh * 8 + 6], e[eh * 8 + 7]);
        asm volatile("v_permlane32_swap_b32 %0, %1" : "+v"(a0), "+v"(b0));
        asm volatile("v_permlane32_swap_b32 %0, %1" : "+v"(a1), "+v"(b1));
        u32x4 pu; pu.x = a0; pu.y = a1; pu.z = b0; pu.w = b1;
        bf16x8 pf = __builtin_bit_cast(bf16x8, pu);
        const size_t vo = (size_t)s * 32 + eh * 16;
        bf16x8 vf0 = *(const bf16x8*)(Vbase0 + vo);
        bf16x8 vf1 = *(const bf16x8*)(Vbase1 + vo);
        o0 = __builtin_amdgcn_mfma_f32_32x32x16_bf16(vf0, pf, o0, 0, 0, 0);
        o1 = __builtin_amdgcn_mfma_f32_32x32x16_bf16(vf1, pf, o1, 0, 0, 0);
      }
    };

    // this wave's sub-tiles: s parity == w; masked one (s == qb) to matching wave
    for (int s = w; s < qb; s += 2) subtile(s, false);
    if ((qb & 1) == w) subtile(qb, true);

    // combine across the 2 waves: wave w keeps d-half w, gives the other half
    float ps = (ps0 + ps1) + (ps2 + ps3);
    const f32x16 give = w ? o0 : o1;
#pragma unroll
    for (int i = 0; i < 16; i++) xo[ph][w][l][i] = give[i];
    xps[ph][w][l] = ps;
    __syncthreads();
    f32x16 keep = w ? o1 : o0;
#pragma unroll
    for (int i = 0; i < 16; i++) keep[i] += xo[ph][1 - w][l][i];
    float pst = ps + xps[ph][1 - w][l];
    pst += __shfl_xor(pst, 32, 64);
    const float inv = 1.f / pst;

    u16* crow = ctx + (size_t)(b * T_ + qa) * D_ + h * HD_ + w * 32;
#pragma unroll
    for (int g = 0; g < 4; g++) {
      int d = g * 8 + 4 * hi;
      uint2 so;
      so.x = cvtpk(keep[g * 4 + 0] * inv, keep[g * 4 + 1] * inv);
      so.y = cvtpk(keep[g * 4 + 2] * inv, keep[g * 4 + 3] * inv);
      *(uint2*)(crow + d) = so;
    }
  }
}

extern "C" void kernel_launch(void* const* d_in, const int* in_sizes, int n_in,
                              void* d_out, int out_size, void* d_ws, size_t ws_size,
                              hipStream_t stream) {
  const float* x  = (const float*)d_in[0];
  const float* Wq = (const float*)d_in[1];
  const float* Wk = (const float*)d_in[2];
  const float* Wv = (const float*)d_in[3];
  const float* Wo = (const float*)d_in[4];
  const float* bo = (const float*)d_in[5];
  float* out = (float*)d_out;

  char* ws = (char*)d_ws;
  u16* Xb     = (u16*)(ws);                   // 16 MB
  u16* WqkvT  = (u16*)(ws + 16777216);        // 6 MB  [3072][1024]
  u16* WoT    = (u16*)(ws + 23068672);        // 2 MB
  u16* Qb     = (u16*)(ws + 25165824);        // 16 MB
  u16* Kb     = (u16*)(ws + 41943040);        // 16 MB
  u16* Vb     = (u16*)(ws + 58720256);        // 16 MB
  u16* Vtb    = (u16*)(ws + 75497472);        // 16 MB
  u16* Cb     = (u16*)(ws + 92274688);        // 16 MB

  k_convert_x<<<dim3(2048), dim3(256), 0, stream>>>(x, Xb);
  k_transpose_w<<<dim3(32, 32, 4), dim3(256), 0, stream>>>(Wq, Wk, Wv, Wo, WqkvT, WoT);
  k_gemm_qkv<<<dim3(24, 64), dim3(256), 0, stream>>>(Xb, WqkvT, Qb, Kb, Vb);
  k_transpose_v<<<dim3(32, 64), dim3(256), 0, stream>>>(Vb, Vtb);
  k_flash<<<dim3(2048), dim3(128), 0, stream>>>(Qb, Kb, Vtb, Cb);
  k_gemm_out<<<dim3(8, 64), dim3(256), 0, stream>>>(Cb, WoT, bo, out);
}